// Round 6
// baseline (256.849 us; speedup 1.0000x reference)
//
#include <hip/hip_runtime.h>
#include <hip/hip_bf16.h>

#define N_BOXES 8192
#define NW 128            // number of 64-box chunks / 64-bit words per row
#define FEAT 10
#define CJG 8             // cj columns per mask block
#define HSLOTS 4          // in-flight gather slots per worker lane (448*4 = 1792)

typedef unsigned long long u64;
typedef unsigned int u32;
typedef unsigned short u16;

__device__ __forceinline__ void barrier_nodrain() {
    asm volatile("s_waitcnt lgkmcnt(0)" ::: "memory");
    __builtin_amdgcn_sched_barrier(0);
    __builtin_amdgcn_s_barrier();
    __builtin_amdgcn_sched_barrier(0);
    asm volatile("" ::: "memory");
}

// ---------------- Phase A: rank + scatter sorted boxes ----------------
// Descending-score order, ties broken by larger original index first
// (matches jnp.argsort(stable)[::-1]).
__global__ void rank_scatter_kernel(const float* __restrict__ bboxes,
                                    const float* __restrict__ scores,
                                    float* __restrict__ x1s, float* __restrict__ y1s,
                                    float* __restrict__ x2s, float* __restrict__ y2s,
                                    u32* __restrict__ rank_of) {
    __shared__ float sc[N_BOXES];
    int tid = threadIdx.x;
    for (int t = 0; t < N_BOXES / 256; ++t)
        sc[tid + 256 * t] = scores[tid + 256 * t];
    __syncthreads();
    int k = tid >> 3;          // box slot 0..31
    int s = tid & 7;           // segment 0..7
    int i = blockIdx.x * 32 + k;
    float si = sc[i];
    int cnt = 0;
    const float4* sc4 = (const float4*)sc;
    int q0 = s * (N_BOXES / 32);
    #pragma unroll 4
    for (int q = q0; q < q0 + N_BOXES / 32; ++q) {
        float4 v = sc4[q];
        int j = 4 * q;
        cnt += (int)((v.x > si) || (v.x == si && j     > i));
        cnt += (int)((v.y > si) || (v.y == si && j + 1 > i));
        cnt += (int)((v.z > si) || (v.z == si && j + 2 > i));
        cnt += (int)((v.w > si) || (v.w == si && j + 3 > i));
    }
    cnt += __shfl_down(cnt, 4, 8);
    cnt += __shfl_down(cnt, 2, 8);
    cnt += __shfl_down(cnt, 1, 8);
    if (s == 0) {
        int r = cnt;
        float x = bboxes[4 * i + 0], y = bboxes[4 * i + 1];
        float w = bboxes[4 * i + 2], h = bboxes[4 * i + 3];
        float x2 = x + w, y2 = y + h;           // exact ref op order
        x1s[r] = x; y1s[r] = y; x2s[r] = x2; y2s[r] = y2;
        rank_of[i] = (u32)r;
    }
}

// ---------------- Phase B: suppression bitmask matrix ----------------
// Row-major: RM[i*NW + cj] = word over j in chunk cj of sup(i->j) (j>i).
// TRb[d*N + j] (d=0,1,2) = word over i in chunk (chunk(j)-d) of sup(i->j).
// Block = (8-cj group, ci); 4 waves x 2 cj each; 64x8 u64 tile in LDS,
// stored coalesced (64B contiguous per row).
__global__ void __launch_bounds__(256) mask_kernel(
        const float* __restrict__ x1s, const float* __restrict__ y1s,
        const float* __restrict__ x2s, const float* __restrict__ y2s,
        u64* __restrict__ RM, u64* __restrict__ TRb) {
    int ci = blockIdx.y;
    int cjg0 = blockIdx.x * CJG;
    if (cjg0 + CJG - 1 < ci) return;     // whole group below diagonal
    __shared__ u64 T[64][CJG];           // 4 KiB tile
    __shared__ float SB[4][4][64];       // per-wave staging of looped chunk
    int wv = threadIdx.x >> 6, lane = threadIdx.x & 63;
    int ig0 = ci * 64;
    // per-lane i-chunk box data (row = lane)
    float ix1 = x1s[ig0 + lane], iy1 = y1s[ig0 + lane];
    float ix2 = x2s[ig0 + lane], iy2 = y2s[ig0 + lane];
    float iar = (ix2 - ix1) * (iy2 - iy1);    // bit-identical to ref area
    #pragma unroll
    for (int t = 0; t < 2; ++t) {
        int cjrel = wv * 2 + t;
        int cj = cjg0 + cjrel;
        if (cj < ci) { T[lane][cjrel] = 0; continue; }
        int jg0 = cj * 64;
        int d = cj - ci;
        if (d <= 2) {
            // ballot path: lanes = columns j; i-chunk staged in LDS
            SB[wv][0][lane] = ix1; SB[wv][1][lane] = iy1;
            SB[wv][2][lane] = ix2; SB[wv][3][lane] = iy2;
            int jg = jg0 + lane;
            float jx1 = x1s[jg], jy1 = y1s[jg], jx2 = x2s[jg], jy2 = y2s[jg];
            float jar = (jx2 - jx1) * (jy2 - jy1);
            u64 my = 0, cw = 0;
            for (int ip = 0; ip < 64; ++ip) {
                float ax1 = SB[wv][0][ip], ay1 = SB[wv][1][ip];
                float ax2 = SB[wv][2][ip], ay2 = SB[wv][3][ip];
                float aar = (ax2 - ax1) * (ay2 - ay1);
                float xx1 = fmaxf(ax1, jx1);
                float yy1 = fmaxf(ay1, jy1);
                float xx2 = fminf(ax2, jx2);
                float yy2 = fminf(ay2, jy2);
                float iw = fmaxf(xx2 - xx1, 0.0f);
                float ih = fmaxf(yy2 - yy1, 0.0f);
                float inter = iw * ih;
                float uni = aar + jar - inter;
                float iou = __fdiv_rn(inter, uni);   // IEEE-exact like numpy
                bool sup = (iou > 0.5f) && (jg > ig0 + ip);
                u64 w = __ballot(sup);
                if (lane == ip) my = w;
                cw |= sup ? (1ull << ip) : 0ull;
            }
            T[lane][cjrel] = my;
            TRb[(size_t)d * N_BOXES + jg] = cw;
        } else {
            // direct path: lanes = rows i; j-chunk staged in LDS
            SB[wv][0][lane] = x1s[jg0 + lane];
            SB[wv][1][lane] = y1s[jg0 + lane];
            SB[wv][2][lane] = x2s[jg0 + lane];
            SB[wv][3][lane] = y2s[jg0 + lane];
            u64 my = 0;
            for (int jp = 0; jp < 64; ++jp) {
                float jx1 = SB[wv][0][jp], jy1 = SB[wv][1][jp];
                float jx2 = SB[wv][2][jp], jy2 = SB[wv][3][jp];
                float jar = (jx2 - jx1) * (jy2 - jy1);
                float xx1 = fmaxf(ix1, jx1);
                float yy1 = fmaxf(iy1, jy1);
                float xx2 = fminf(ix2, jx2);
                float yy2 = fminf(iy2, jy2);
                float iw = fmaxf(xx2 - xx1, 0.0f);
                float ih = fmaxf(yy2 - yy1, 0.0f);
                float inter = iw * ih;
                float uni = iar + jar - inter;
                float iou = __fdiv_rn(inter, uni);
                bool sup = (iou > 0.5f);             // cj>ci+2 => j>i always
                my |= sup ? (1ull << jp) : 0ull;
            }
            T[lane][cjrel] = my;
        }
    }
    __syncthreads();
    // coalesced tile store: 16B per thread, 64B contiguous per row
    int row = threadIdx.x >> 2, p = threadIdx.x & 3;
    ulonglong2 v;
    v.x = T[row][2 * p];
    v.y = T[row][2 * p + 1];
    *(ulonglong2*)&RM[(size_t)(ig0 + row) * NW + cjg0 + 2 * p] = v;
}

// ---------------- Phase C+D: greedy reduce (1 block) + fused output ---------
// Kept-list gather design. Per region c (one barrier):
//  wave0: ballot-fixpoint for chunk c. base = rem32[c] (kept chunks <= c-3,
//         built by the gather) + register folds d=1 (chunk c-1) / d=2 (c-2)
//         from TR planes prefetched 2 regions ahead (A/B sets, no copies).
//         Appends kept box ids to klist (LDS u16), publishes ktot[c].
//  waves 1-7 (448 lanes): COMMIT word c+1 (gather loads issued last region,
//         held in H[4]) via 3-level shfl-OR + fire-and-forget LDS atomics;
//         then ISSUE gather loads for word c+2 over klist[0..ktot[c-1]).
__global__ void __launch_bounds__(512) nms_reduce_fused(
        const u64* __restrict__ RM, const u64* __restrict__ TRb,
        const u32* __restrict__ rank_of,
        const float* __restrict__ bboxes, const float* __restrict__ features,
        const float* __restrict__ Wm, const float* __restrict__ bv,
        const int* __restrict__ widthp, const int* __restrict__ heightp,
        float* __restrict__ out) {
    __shared__ u32 rem32[NW * 2];
    __shared__ u64 keptw[NW];
    __shared__ u16 klist[N_BOXES];
    __shared__ u32 ktot[NW];

    const int tid = threadIdx.x;
    const int wv = tid >> 6, lane = tid & 63;
    if (tid < NW * 2) rem32[tid] = 0;

    // wave0 persistent state: TR register sets (A = even chunks, B = odd)
    u64 tdA = 0, t1A = 0, t2A = 0, tdB = 0, t1B = 0, t2B = 0;
    u64 kp1 = 0, kp2 = 0;
    u32 krun = 0;
    if (wv == 0) {
        tdA = TRb[lane];                          // d0 chunk0
        t1A = TRb[N_BOXES + lane];                // d1 chunk0 (garbage, kp1=0)
        t2A = TRb[2 * N_BOXES + lane];            // d2 chunk0 (garbage, kp2=0)
        tdB = TRb[64 + lane];
        t1B = TRb[N_BOXES + 64 + lane];
        t2B = TRb[2 * N_BOXES + 64 + lane];       // d2 chunk1 (garbage, kp2=0)
    }
    // worker persistent state
    u64 H0_ = 0, H1_ = 0, H2_ = 0, H3_ = 0;
    u32 kcP = 0;
    const u32 lg = (u32)((wv - 1) * 64 + lane);   // gather lane 0..447 (wv>=1)
    __syncthreads();

#define REGION(C, TD, T1, T2)                                                  \
    do {                                                                       \
        const int c_ = (C);                                                    \
        if (wv == 0) {                                                         \
            u64 base = ((u64)rem32[2 * c_ + 1] << 32) | (u64)rem32[2 * c_];    \
            u64 R = base | __ballot(((T1 & kp1) | (T2 & kp2)) != 0ull);        \
            u64 K = 0, U = ~R;                                                 \
            bool meU = (U >> lane) & 1;                                        \
            while (U) {                                                        \
                u64 UK = U | K;                                                \
                u64 nK = __ballot(meU && ((TD & UK) == 0ull));                 \
                K |= nK;                                                       \
                u64 nR = __ballot(meU && ((TD & K) != 0ull));                  \
                U &= ~(K | nR);                                                \
                meU = (U >> lane) & 1;                                         \
            }                                                                  \
            bool isk = (K >> lane) & 1;                                        \
            int rnk = __popcll(K & ((1ull << lane) - 1ull));                   \
            if (isk) klist[krun + rnk] = (u16)(c_ * 64 + lane);                \
            krun += (u32)__popcll(K);                                          \
            if (lane == 0) { keptw[c_] = K; ktot[c_] = krun; }                 \
            kp2 = kp1; kp1 = K;                                                \
            if (c_ + 2 < NW) {                                                 \
                TD = TRb[(c_ + 2) * 64 + lane];                                \
                T1 = TRb[N_BOXES + (c_ + 2) * 64 + lane];                      \
                T2 = TRb[2 * N_BOXES + (c_ + 2) * 64 + lane];                  \
            }                                                                  \
        } else {                                                               \
            /* COMMIT word c_+1 (gather issued last region, held in H) */      \
            if (c_ >= 2) {                                                     \
                u64 acc = H0_ | H1_ | H2_ | H3_;                               \
                for (u32 e = lg + 448u * HSLOTS; e < kcP; e += 448u)           \
                    acc |= RM[(size_t)klist[e] * NW + (c_ + 1)];               \
                acc |= __shfl_xor(acc, 1, 64);                                 \
                acc |= __shfl_xor(acc, 2, 64);                                 \
                acc |= __shfl_xor(acc, 4, 64);                                 \
                if ((lane & 7) == 0 && acc) {                                  \
                    atomicOr(&rem32[2 * (c_ + 1)],     (u32)acc);              \
                    atomicOr(&rem32[2 * (c_ + 1) + 1], (u32)(acc >> 32));      \
                }                                                              \
            }                                                                  \
            /* ISSUE gather for word c_+2 over kept chunks <= c_-1 */          \
            H0_ = 0; H1_ = 0; H2_ = 0; H3_ = 0;                                \
            if (c_ >= 1 && c_ + 2 < NW) {                                      \
                kcP = ktot[c_ - 1];                                            \
                if (lg < kcP)                                                  \
                    H0_ = RM[(size_t)klist[lg] * NW + (c_ + 2)];               \
                if (lg + 448u < kcP)                                           \
                    H1_ = RM[(size_t)klist[lg + 448u] * NW + (c_ + 2)];        \
                if (lg + 896u < kcP)                                           \
                    H2_ = RM[(size_t)klist[lg + 896u] * NW + (c_ + 2)];        \
                if (lg + 1344u < kcP)                                          \
                    H3_ = RM[(size_t)klist[lg + 1344u] * NW + (c_ + 2)];       \
            } else kcP = 0;                                                    \
        }                                                                      \
        barrier_nodrain();                                                     \
    } while (0)

    for (int cc = 0; cc < NW; cc += 2) {
        REGION(cc,     tdA, t1A, t2A);
        REGION(cc + 1, tdB, t1B, t2B);
    }
#undef REGION

    __syncthreads();

    // ---------------- fused output tail ----------------
    float wreg[FEAT * 4];
    #pragma unroll
    for (int m = 0; m < FEAT * 4; ++m) wreg[m] = Wm[m];
    float bb0 = bv[0], bb1 = bv[1], bb2 = bv[2], bb3 = bv[3];
    float sw = (float)(*widthp), sh = (float)(*heightp);
    for (int k = 0; k < N_BOXES / 512; ++k) {
        int i = tid + 512 * k;
        u32 r = rank_of[i];
        float keep = (float)((keptw[r >> 6] >> (r & 63)) & 1ull);
        float z0 = bb0, z1 = bb1, z2 = bb2, z3 = bb3;
        #pragma unroll
        for (int m = 0; m < FEAT; ++m) {
            float f = features[i * FEAT + m];
            z0 += f * wreg[m * 4 + 0];
            z1 += f * wreg[m * 4 + 1];
            z2 += f * wreg[m * 4 + 2];
            z3 += f * wreg[m * 4 + 3];
        }
        float t0 = 1.0f / (1.0f + expf(-z0));
        float t1 = 1.0f / (1.0f + expf(-z1));
        float t2 = 1.0f / (1.0f + expf(-z2));
        float t3 = 1.0f / (1.0f + expf(-z3));
        float4 bx = ((const float4*)bboxes)[i];
        float ox = fmaxf(t0 * bx.z + bx.x, 0.0f);
        float oy = fmaxf(t1 * bx.w + bx.y, 0.0f);
        float ow = bx.z * expf(t2);
        float oh = bx.w * expf(t3);
        float4 o;
        o.x = ox * sw * keep;
        o.y = oy * sh * keep;
        o.z = ow * sw * keep;
        o.w = oh * sh * keep;
        ((float4*)out)[i] = o;
    }
}

extern "C" void kernel_launch(void* const* d_in, const int* in_sizes, int n_in,
                              void* d_out, int out_size, void* d_ws, size_t ws_size,
                              hipStream_t stream) {
    const float* bboxes   = (const float*)d_in[0];
    const float* scores   = (const float*)d_in[1];
    const float* features = (const float*)d_in[2];
    const float* Wm       = (const float*)d_in[3];
    const float* bv       = (const float*)d_in[4];
    const int*   widthp   = (const int*)d_in[5];
    const int*   heightp  = (const int*)d_in[6];
    float* out = (float*)d_out;

    char* ws = (char*)d_ws;
    u64* RM      = (u64*)ws;                                        // 8 MiB
    u64* TRb     = (u64*)(ws + (size_t)N_BOXES * NW * sizeof(u64)); // 192 KiB
    float* x1s   = (float*)((char*)TRb + (size_t)3 * N_BOXES * sizeof(u64));
    float* y1s   = x1s + N_BOXES;
    float* x2s   = y1s + N_BOXES;
    float* y2s   = x2s + N_BOXES;
    u32* rank_of = (u32*)(y2s + N_BOXES);

    rank_scatter_kernel<<<N_BOXES / 32, 256, 0, stream>>>(bboxes, scores,
                                                          x1s, y1s, x2s, y2s, rank_of);
    mask_kernel<<<dim3(NW / CJG, NW), 256, 0, stream>>>(x1s, y1s, x2s, y2s, RM, TRb);
    nms_reduce_fused<<<1, 512, 0, stream>>>(RM, TRb, rank_of, bboxes, features,
                                            Wm, bv, widthp, heightp, out);
}

// Round 8
// 162.191 us; speedup vs baseline: 1.5836x; 1.5836x over previous
//
#include <hip/hip_runtime.h>
#include <hip/hip_bf16.h>

#define N_BOXES 8192
#define NW 128            // number of 64-box chunks / 64-bit words per row
#define FEAT 10
#define NSLOT 4           // row slots per lane; 7 groups * 4 = 28 rows capacity

typedef unsigned long long u64;
typedef unsigned int u32;

__device__ __forceinline__ void barrier_nodrain() {
    asm volatile("s_waitcnt lgkmcnt(0)" ::: "memory");
    __builtin_amdgcn_sched_barrier(0);
    __builtin_amdgcn_s_barrier();
    __builtin_amdgcn_sched_barrier(0);
    asm volatile("" ::: "memory");
}

// ---------------- Phase A: rank + scatter sorted boxes ----------------
// Descending-score order, ties broken by larger original index first
// (matches jnp.argsort(stable)[::-1]).
__global__ void rank_scatter_kernel(const float* __restrict__ bboxes,
                                    const float* __restrict__ scores,
                                    float* __restrict__ x1s, float* __restrict__ y1s,
                                    float* __restrict__ x2s, float* __restrict__ y2s,
                                    u32* __restrict__ rank_of) {
    __shared__ float sc[N_BOXES];
    int tid = threadIdx.x;
    for (int t = 0; t < N_BOXES / 256; ++t)
        sc[tid + 256 * t] = scores[tid + 256 * t];
    __syncthreads();
    int k = tid >> 3;          // box slot 0..31
    int s = tid & 7;           // segment 0..7
    int i = blockIdx.x * 32 + k;
    float si = sc[i];
    int cnt = 0;
    const float4* sc4 = (const float4*)sc;
    int q0 = s * (N_BOXES / 32);
    #pragma unroll 4
    for (int q = q0; q < q0 + N_BOXES / 32; ++q) {
        float4 v = sc4[q];
        int j = 4 * q;
        cnt += (int)((v.x > si) || (v.x == si && j     > i));
        cnt += (int)((v.y > si) || (v.y == si && j + 1 > i));
        cnt += (int)((v.z > si) || (v.z == si && j + 2 > i));
        cnt += (int)((v.w > si) || (v.w == si && j + 3 > i));
    }
    cnt += __shfl_down(cnt, 4, 8);
    cnt += __shfl_down(cnt, 2, 8);
    cnt += __shfl_down(cnt, 1, 8);
    if (s == 0) {
        int r = cnt;
        float x = bboxes[4 * i + 0], y = bboxes[4 * i + 1];
        float w = bboxes[4 * i + 2], h = bboxes[4 * i + 3];
        float x2 = x + w, y2 = y + h;           // exact ref op order
        x1s[r] = x; y1s[r] = y; x2s[r] = x2; y2s[r] = y2;
        rank_of[i] = (u32)r;
    }
}

// ---------------- Phase B: suppression bitmask matrix ----------------
// Row-major: RM[i*NW + cj] = word over j in chunk cj of sup(i->j) (j>i).
// TRb[d*N + j] (d=0,1,2) = word over i in chunk (chunk(j)-d) of sup(i->j).
__global__ void __launch_bounds__(256) mask_kernel(
        const float* __restrict__ x1s, const float* __restrict__ y1s,
        const float* __restrict__ x2s, const float* __restrict__ y2s,
        u64* __restrict__ RM, u64* __restrict__ TRb) {
    int wv = threadIdx.x >> 6, lane = threadIdx.x & 63;
    int ci = blockIdx.x;
    int cj = blockIdx.y * 4 + wv;
    if (cj < ci) return;
    __shared__ float S[4][4][64];
    int d = cj - ci;
    int ig0 = ci * 64, jg0 = cj * 64;
    if (d <= 2) {
        // ballot path: lanes = columns j; i-chunk staged in LDS
        S[wv][0][lane] = x1s[ig0 + lane];
        S[wv][1][lane] = y1s[ig0 + lane];
        S[wv][2][lane] = x2s[ig0 + lane];
        S[wv][3][lane] = y2s[ig0 + lane];
        int jg = jg0 + lane;
        float jx1 = x1s[jg], jy1 = y1s[jg], jx2 = x2s[jg], jy2 = y2s[jg];
        float jar = (jx2 - jx1) * (jy2 - jy1);   // bit-identical to ref area
        u64 my = 0, cw = 0;
        for (int ip = 0; ip < 64; ++ip) {
            float ax1 = S[wv][0][ip], ay1 = S[wv][1][ip];
            float ax2 = S[wv][2][ip], ay2 = S[wv][3][ip];
            float aar = (ax2 - ax1) * (ay2 - ay1);
            float xx1 = fmaxf(ax1, jx1);
            float yy1 = fmaxf(ay1, jy1);
            float xx2 = fminf(ax2, jx2);
            float yy2 = fminf(ay2, jy2);
            float iw = fmaxf(xx2 - xx1, 0.0f);
            float ih = fmaxf(yy2 - yy1, 0.0f);
            float inter = iw * ih;
            float uni = aar + jar - inter;
            float iou = __fdiv_rn(inter, uni);   // IEEE-exact like numpy
            bool sup = (iou > 0.5f) && (jg > ig0 + ip);
            u64 w = __ballot(sup);
            if (lane == ip) my = w;
            cw |= sup ? (1ull << ip) : 0ull;
        }
        RM[(size_t)(ig0 + lane) * NW + cj] = my;
        TRb[(size_t)d * N_BOXES + jg] = cw;
    } else {
        // direct path: lanes = rows i; j-chunk staged in LDS
        S[wv][0][lane] = x1s[jg0 + lane];
        S[wv][1][lane] = y1s[jg0 + lane];
        S[wv][2][lane] = x2s[jg0 + lane];
        S[wv][3][lane] = y2s[jg0 + lane];
        int ig = ig0 + lane;
        float ix1 = x1s[ig], iy1 = y1s[ig], ix2 = x2s[ig], iy2 = y2s[ig];
        float iar = (ix2 - ix1) * (iy2 - iy1);
        u64 my = 0;
        for (int jp = 0; jp < 64; ++jp) {
            float jx1 = S[wv][0][jp], jy1 = S[wv][1][jp];
            float jx2 = S[wv][2][jp], jy2 = S[wv][3][jp];
            float jar = (jx2 - jx1) * (jy2 - jy1);
            float xx1 = fmaxf(ix1, jx1);
            float yy1 = fmaxf(iy1, jy1);
            float xx2 = fminf(ix2, jx2);
            float yy2 = fminf(iy2, jy2);
            float iw = fmaxf(xx2 - xx1, 0.0f);
            float ih = fmaxf(yy2 - yy1, 0.0f);
            float inter = iw * ih;
            float uni = iar + jar - inter;
            float iou = __fdiv_rn(inter, uni);
            bool sup = (iou > 0.5f);             // cj>ci+2 => j>i always
            my |= sup ? (1ull << jp) : 0ull;
        }
        RM[(size_t)ig * NW + cj] = my;
    }
}

// ---------------- Phase C+D: greedy reduce (1 block) + fused output ---------
// Push-kept pipelined design, 7x64x2 lane map (exact cover of 448 lanes):
//  wave0: ballot-fixpoint for chunk c (rem32 base = kept chunks <= c-3;
//         register folds d=1/d=2 cover chunks c-1/c-2 via TR planes
//         prefetched 2 regions ahead). Writes keptw[c] + klist[c&3].
//  waves 1-7: grp = wv-1 (0..6); lane owns words bb+lane and bb+64+lane;
//         rows r = s*7+grp (wave-uniform guards). COMMIT chunk c-2's rows
//         (loaded last region into H) via ds_or_b64; ISSUE chunk c-1's rows.
//         Overflow (kn > 28) -> immediate-load loop at commit (rare).
__global__ void __launch_bounds__(512) nms_reduce_fused(
        const u64* __restrict__ RM, const u64* __restrict__ TRb,
        const u32* __restrict__ rank_of,
        const float* __restrict__ bboxes, const float* __restrict__ features,
        const float* __restrict__ Wm, const float* __restrict__ bv,
        const int* __restrict__ widthp, const int* __restrict__ heightp,
        float* __restrict__ out) {
    __shared__ __align__(8) u32 rem32[NW * 2];
    __shared__ u64 keptw[NW];
    __shared__ unsigned char klist[4][64];

    const int tid = threadIdx.x;
    const int wv = tid >> 6, lane = tid & 63;
    const int grp = wv - 1;                       // 0..6 for workers

    if (tid < NW * 2) rem32[tid] = 0;

    u64 TR0[2], TR1[2], TR2[2];
    u64 kp1 = 0, kp2 = 0;
    if (wv == 0) {
        TR0[0] = TRb[lane];
        TR1[0] = TRb[N_BOXES + lane];             // chunk0 d1: garbage, kp1=0
        TR2[0] = TRb[2 * N_BOXES + lane];         // chunk0 d2: garbage, kp2=0
        TR0[1] = TRb[64 + lane];
        TR1[1] = TRb[N_BOXES + 64 + lane];
        TR2[1] = TRb[2 * N_BOXES + 64 + lane];    // chunk1 d2: garbage, kp2=0
    }
    u64 H0[2][NSLOT], H1[2][NSLOT];
    u32 Kn[2] = {0, 0};
    __syncthreads();

#define REGION(RC, PAR)                                                         \
  do {                                                                          \
    const int c_ = (RC);                                                        \
    if (wv == 0) {                                                              \
      u64 TD = TR0[PAR], T1f = TR1[PAR], T2f = TR2[PAR];                        \
      u64 base = *(const u64*)&rem32[2 * c_];                                   \
      u64 R = base | __ballot(((T1f & kp1) | (T2f & kp2)) != 0ull);             \
      u64 K = 0, U = ~R;                                                        \
      bool meU = (U >> lane) & 1;                                               \
      while (U) {                                                               \
        u64 UK = U | K;                                                         \
        u64 nK = __ballot(meU && ((TD & UK) == 0ull));                          \
        K |= nK;                                                                \
        u64 nR = __ballot(meU && ((TD & K) != 0ull));                           \
        U &= ~(K | nR);                                                         \
        meU = (U >> lane) & 1;                                                  \
      }                                                                         \
      bool isk = (K >> lane) & 1;                                               \
      int rnk = __popcll(K & ((1ull << lane) - 1ull));                          \
      if (isk) klist[c_ & 3][rnk] = (unsigned char)lane;                        \
      if (lane == 0) keptw[c_] = K;                                             \
      kp2 = kp1; kp1 = K;                                                       \
      if (c_ + 2 < NW) {                                                        \
        TR0[PAR] = TRb[(c_ + 2) * 64 + lane];                                   \
        TR1[PAR] = TRb[N_BOXES + (c_ + 2) * 64 + lane];                         \
        TR2[PAR] = TRb[2 * N_BOXES + (c_ + 2) * 64 + lane];                     \
      }                                                                         \
    } else {                                                                    \
      /* COMMIT chunk c_-2 (slots loaded last region); words bb=c_+1 */         \
      if (c_ >= 2 && Kn[PAR] > 0) {                                             \
        const int wd0 = c_ + 1 + lane;                                          \
        const int wd1 = wd0 + 64;                                               \
        u64 v0 = 0, v1 = 0;                                                     \
        _Pragma("unroll")                                                       \
        for (int s = 0; s < NSLOT; ++s) { v0 |= H0[PAR][s]; v1 |= H1[PAR][s]; } \
        u32 kn = Kn[PAR];                                                       \
        if (kn > 7u * NSLOT) {                     /* rare overflow */          \
          const u32 cpb = (u32)(c_ - 2) * 64u;                                  \
          const unsigned char* kl = klist[(c_ + 2) & 3];                        \
          for (u32 r = 7u * NSLOT + (u32)grp; r < kn; r += 7u) {                \
            const u64* rp = RM + (size_t)(cpb + kl[r]) * NW;                    \
            if (wd0 < NW) v0 |= rp[wd0];                                        \
            if (wd1 < NW) v1 |= rp[wd1];                                        \
          }                                                                     \
        }                                                                       \
        if (wd0 < NW && v0) atomicOr((u64*)&rem32[2 * wd0], v0);                \
        if (wd1 < NW && v1) atomicOr((u64*)&rem32[2 * wd1], v1);                \
      }                                                                         \
      /* ISSUE chunk c_-1 (consumed next region); words bb=c_+2 */              \
      {                                                                         \
        const int NP = PAR ^ 1;                                                 \
        const int cp = c_ - 1;                                                  \
        if (cp >= 0 && cp + 3 < NW) {                                           \
          u64 KW = keptw[cp];                                                   \
          u32 kn = (u32)__popcll(KW);                                           \
          Kn[NP] = kn;                                                          \
          const int wi0 = c_ + 2 + lane;                                        \
          const int wi1 = wi0 + 64;                                             \
          const unsigned char* kl = klist[(c_ + 3) & 3];                        \
          const u32 cpb = (u32)cp * 64u;                                        \
          _Pragma("unroll")                                                     \
          for (int s = 0; s < NSLOT; ++s) {                                     \
            H0[NP][s] = 0; H1[NP][s] = 0;                                       \
            u32 r = (u32)(s * 7 + grp);            /* wave-uniform */           \
            if (r < kn) {                                                       \
              const u64* rp = RM + (size_t)(cpb + kl[r]) * NW;                  \
              if (wi0 < NW) H0[NP][s] = rp[wi0];                                \
              if (wi1 < NW) H1[NP][s] = rp[wi1];                                \
            }                                                                   \
          }                                                                     \
        } else Kn[NP] = 0;                                                      \
      }                                                                         \
    }                                                                           \
    barrier_nodrain();                                                          \
  } while (0)

    for (int cc = 0; cc < NW; cc += 2) {
        REGION(cc, 0);
        REGION(cc + 1, 1);
    }
#undef REGION

    __syncthreads();

    // ---------------- fused output tail ----------------
    float wreg[FEAT * 4];
    #pragma unroll
    for (int m = 0; m < FEAT * 4; ++m) wreg[m] = Wm[m];
    float bb0 = bv[0], bb1 = bv[1], bb2 = bv[2], bb3 = bv[3];
    float sw = (float)(*widthp), sh = (float)(*heightp);
    for (int k = 0; k < N_BOXES / 512; ++k) {
        int i = tid + 512 * k;
        u32 r = rank_of[i];
        float keep = (float)((keptw[r >> 6] >> (r & 63)) & 1ull);
        float z0 = bb0, z1 = bb1, z2 = bb2, z3 = bb3;
        #pragma unroll
        for (int m = 0; m < FEAT; ++m) {
            float f = features[i * FEAT + m];
            z0 += f * wreg[m * 4 + 0];
            z1 += f * wreg[m * 4 + 1];
            z2 += f * wreg[m * 4 + 2];
            z3 += f * wreg[m * 4 + 3];
        }
        float t0 = 1.0f / (1.0f + expf(-z0));
        float t1 = 1.0f / (1.0f + expf(-z1));
        float t2 = 1.0f / (1.0f + expf(-z2));
        float t3 = 1.0f / (1.0f + expf(-z3));
        float4 bx = ((const float4*)bboxes)[i];
        float ox = fmaxf(t0 * bx.z + bx.x, 0.0f);
        float oy = fmaxf(t1 * bx.w + bx.y, 0.0f);
        float ow = bx.z * expf(t2);
        float oh = bx.w * expf(t3);
        float4 o;
        o.x = ox * sw * keep;
        o.y = oy * sh * keep;
        o.z = ow * sw * keep;
        o.w = oh * sh * keep;
        ((float4*)out)[i] = o;
    }
}

extern "C" void kernel_launch(void* const* d_in, const int* in_sizes, int n_in,
                              void* d_out, int out_size, void* d_ws, size_t ws_size,
                              hipStream_t stream) {
    const float* bboxes   = (const float*)d_in[0];
    const float* scores   = (const float*)d_in[1];
    const float* features = (const float*)d_in[2];
    const float* Wm       = (const float*)d_in[3];
    const float* bv       = (const float*)d_in[4];
    const int*   widthp   = (const int*)d_in[5];
    const int*   heightp  = (const int*)d_in[6];
    float* out = (float*)d_out;

    char* ws = (char*)d_ws;
    u64* RM      = (u64*)ws;                                        // 8 MiB
    u64* TRb     = (u64*)(ws + (size_t)N_BOXES * NW * sizeof(u64)); // 192 KiB
    float* x1s   = (float*)((char*)TRb + (size_t)3 * N_BOXES * sizeof(u64));
    float* y1s   = x1s + N_BOXES;
    float* x2s   = y1s + N_BOXES;
    float* y2s   = x2s + N_BOXES;
    u32* rank_of = (u32*)(y2s + N_BOXES);

    rank_scatter_kernel<<<N_BOXES / 32, 256, 0, stream>>>(bboxes, scores,
                                                          x1s, y1s, x2s, y2s, rank_of);
    mask_kernel<<<dim3(NW, NW / 4), 256, 0, stream>>>(x1s, y1s, x2s, y2s, RM, TRb);
    nms_reduce_fused<<<1, 512, 0, stream>>>(RM, TRb, rank_of, bboxes, features,
                                            Wm, bv, widthp, heightp, out);
}